// Round 5
// baseline (74.830 us; speedup 1.0000x reference)
//
#include <hip/hip_runtime.h>
#include <stdint.h>

#define A_DIM 8192
#define B_DIM 8192
#define K_CL  256
#define BM    64
#define BK    64
#define NSLAB 4
#define SLABW (B_DIM / NSLAB)   // 2048
#define NKS   (SLABW / BK)      // 32

typedef short bf16x8 __attribute__((ext_vector_type(8)));
typedef float f32x4  __attribute__((ext_vector_type(4)));
typedef float f32x16 __attribute__((ext_vector_type(16)));
typedef unsigned short u16;

__device__ __forceinline__ u16 f2bf(float f) {
    unsigned int u = __float_as_uint(f);
    u += 0x7fffu + ((u >> 16) & 1u);   // RNE, finite inputs (prep only)
    return (u16)(u >> 16);
}

// ---------- prep: pack p_r into 32x32x16 MFMA B-fragment layout, bf16 ----------
// B-frag element map (32x32x16): col = lane&31, k = (lane>>5)*8 + j
// Bpack[((kb2*8 + c2)*64 + lane)*8 + j] = bf16(p_r[kb2*16 + (lane>>5)*8 + j][c2*32 + (lane&31)])
// kb2 = k16-block (0..511), c2 = col32-block (0..7). Total 4 MB.
__global__ __launch_bounds__(256) void k_prep(const float* __restrict__ pr,
                                              u16* __restrict__ Bpack,
                                              float* __restrict__ out) {
    const int kb2 = blockIdx.x;          // 0..511
    const int t = threadIdx.x;
    if (kb2 == 0 && t == 0) out[0] = 0.0f;
    const int lane = t & 63, wv = t >> 6;
    const int l31 = lane & 31, half = lane >> 5;
#pragma unroll
    for (int ci = 0; ci < 2; ci++) {
        const int c2 = wv * 2 + ci;
        float v[8];
#pragma unroll
        for (int j = 0; j < 8; j++)
            v[j] = pr[(size_t)(kb2 * 16 + half * 8 + j) * K_CL + c2 * 32 + l31];
        union { bf16x8 b; unsigned int u[4]; } o;
#pragma unroll
        for (int j = 0; j < 4; j++)
            o.u[j] = (unsigned int)f2bf(v[2 * j]) | ((unsigned int)f2bf(v[2 * j + 1]) << 16);
        *(bf16x8*)(Bpack + ((size_t)(kb2 * 8 + c2) * 64 + lane) * 8) = o.b;
    }
}

// ---------- main ----------
__global__ __launch_bounds__(256, 2) void k_main(const float* __restrict__ w,
                                                 const float* __restrict__ pl,
                                                 const u16* __restrict__ Bpack,
                                                 const float* __restrict__ cp,
                                                 float* __restrict__ out) {
    __shared__ float Abuf[4][BM * BK];   // 4 x 16 KB, row = 256 B, source-swizzled
    __shared__ float rowsum[BM];         // slab-partial row sums of w
    __shared__ float red[4];

    const int bid = blockIdx.x;
    const int slab = bid & 3;
    const int m0 = (bid >> 2) * BM;
    const int tid = threadIdx.x;
    const int lane = tid & 63, wv = tid >> 6;
    const int l31 = lane & 31, half = lane >> 5;
    const int kb2base = slab * 128;

    if (tid < BM) rowsum[tid] = 0.0f;

    float rcp_cp[2];
#pragma unroll
    for (int n2 = 0; n2 < 2; n2++)
        rcp_cp[n2] = 1.0f / cp[wv * 64 + n2 * 32 + l31];

    __syncthreads();   // rowsum zeroed (prologue only)

    const char* wbase = (const char*)(w + (size_t)m0 * B_DIM + (size_t)slab * SLABW);

    // stage [64 rows][64 f32] of w via global_load_lds: linear LDS dest,
    // inverse-XOR-swizzled ((row&15)<<4) per-lane global SOURCE
    auto stage = [&](int buf, int ks) {
#pragma unroll
        for (int i = 0; i < 4; i++) {
            const int r4 = tid >> 4;                 // 0..15 == row&15
            const int sw = r4 << 4;
            const char* src = wbase + (size_t)(i * 16 + r4) * (B_DIM * 4) + ks * 256 + (((tid & 15) * 16) ^ sw);
            void* dst = (void*)&Abuf[buf][i * 1024 + (tid >> 4) * 64 + (tid & 15) * 4];
            __builtin_amdgcn_global_load_lds(
                (const __attribute__((address_space(1))) void*)src,
                (__attribute__((address_space(3))) void*)dst, 16, 0, 0);
        }
    };

#define LOADB(arr, ks) do {                                                              \
        _Pragma("unroll")                                                                \
        for (int kf_ = 0; kf_ < 4; kf_++)                                                \
            _Pragma("unroll")                                                            \
            for (int n2_ = 0; n2_ < 2; n2_++)                                            \
                (arr)[kf_ * 2 + n2_] = *(const bf16x8*)(Bpack +                          \
                    (((size_t)(kb2base + (ks) * 4 + kf_) * 8 + wv * 2 + n2_) * 64 + lane) * 8); \
    } while (0)

#define COMPUTE(cur, arr) do {                                                           \
        const char* abase_ = (const char*)&Abuf[(cur)][0];                               \
        const int sw_ = (l31 & 15) << 4;                                                 \
        _Pragma("unroll")                                                                \
        for (int kf_ = 0; kf_ < 4; kf_++) {                                              \
            bf16x8 a_[2];                                                                \
            f32x4 f0_[2], f1_[2];                                                        \
            _Pragma("unroll")                                                            \
            for (int mf_ = 0; mf_ < 2; mf_++) {                                          \
                const char* rp_ = abase_ + (mf_ * 32 + l31) * 256;                       \
                f0_[mf_] = *(const f32x4*)(rp_ + ((kf_ * 64 + half * 32) ^ sw_));        \
                f1_[mf_] = *(const f32x4*)(rp_ + ((kf_ * 64 + half * 32 + 16) ^ sw_));   \
                union { bf16x8 v; unsigned int u[4]; } pa_;                              \
                pa_.u[0] = __builtin_amdgcn_perm(__float_as_uint(f0_[mf_][1]), __float_as_uint(f0_[mf_][0]), 0x07060302u); \
                pa_.u[1] = __builtin_amdgcn_perm(__float_as_uint(f0_[mf_][3]), __float_as_uint(f0_[mf_][2]), 0x07060302u); \
                pa_.u[2] = __builtin_amdgcn_perm(__float_as_uint(f1_[mf_][1]), __float_as_uint(f1_[mf_][0]), 0x07060302u); \
                pa_.u[3] = __builtin_amdgcn_perm(__float_as_uint(f1_[mf_][3]), __float_as_uint(f1_[mf_][2]), 0x07060302u); \
                a_[mf_] = pa_.v;                                                         \
            }                                                                            \
            if (kf_ == wv) {   /* balanced: wave wv owns k-quarter kf==wv */             \
                sums0 += f0_[0][0]+f0_[0][1]+f0_[0][2]+f0_[0][3]+f1_[0][0]+f1_[0][1]+f1_[0][2]+f1_[0][3]; \
                sums1 += f0_[1][0]+f0_[1][1]+f0_[1][2]+f0_[1][3]+f1_[1][0]+f1_[1][1]+f1_[1][2]+f1_[1][3]; \
            }                                                                            \
            _Pragma("unroll")                                                            \
            for (int mf_ = 0; mf_ < 2; mf_++)                                            \
                _Pragma("unroll")                                                        \
                for (int n2_ = 0; n2_ < 2; n2_++)                                        \
                    acc[mf_ * 2 + n2_] = __builtin_amdgcn_mfma_f32_32x32x16_bf16(        \
                        a_[mf_], (arr)[kf_ * 2 + n2_], acc[mf_ * 2 + n2_], 0, 0, 0);     \
        }                                                                                \
    } while (0)

#define BODY(ks, WAITN, BCUR, BNXT, DOSTAGE, DOLOADB) do {                               \
        asm volatile("s_waitcnt vmcnt(" #WAITN ")" ::: "memory");                        \
        __builtin_amdgcn_s_barrier();                                                    \
        __builtin_amdgcn_sched_barrier(0);                                               \
        if (DOLOADB) LOADB(BNXT, (ks) + 1);                                              \
        if (DOSTAGE) stage(((ks) + 3) & 3, (ks) + 3);                                    \
        COMPUTE((ks) & 3, BCUR);                                                         \
    } while (0)

    f32x16 acc[4];
#pragma unroll
    for (int i = 0; i < 4; i++)
#pragma unroll
        for (int r = 0; r < 16; r++) acc[i][r] = 0.f;
    float sums0 = 0.f, sums1 = 0.f;

    bf16x8 bA[8], bB[8];
    stage(0, 0); stage(1, 1); stage(2, 2);
    LOADB(bA, 0);

    for (int ks = 0; ks < NKS - 4; ks += 2) {   // ks = 0..27
        BODY(ks,     16, bA, bB, 1, 1);
        BODY(ks + 1, 16, bB, bA, 1, 1);
    }
    BODY(28, 16, bA, bB, 1, 1);   // stages S31, loads B29
    BODY(29, 16, bB, bA, 0, 1);   // loads B30
    BODY(30, 12, bA, bB, 0, 1);   // loads B31
    BODY(31,  8, bB, bA, 0, 0);

#undef BODY
#undef COMPUTE
#undef LOADB

    // merge per-wave k-partial row sums (lane and lane+32 hold the two k-halves)
    {
        float v0 = sums0 + __shfl_xor(sums0, 32, 64);
        float v1 = sums1 + __shfl_xor(sums1, 32, 64);
        if (lane < 32) {
            atomicAdd(&rowsum[l31], v0);
            atomicAdd(&rowsum[32 + l31], v1);
        }
    }
    __syncthreads();

    // epilogue: tot = sum over (row,col) of [q*(1-2p) + rowW_slab*p] / cp
    // C/D 32x32 layout: col = lane&31, row = (reg&3) + 8*(reg>>2) + 4*(lane>>5)
    float tot = 0.f;
#pragma unroll
    for (int mf = 0; mf < 2; mf++) {
#pragma unroll
        for (int reg = 0; reg < 16; reg++) {
            const int lrow = mf * 32 + (reg & 3) + 8 * (reg >> 2) + 4 * half;
            const float rs = rowsum[lrow];
            const float* plrow = pl + (size_t)(m0 + lrow) * K_CL + wv * 64 + l31;
#pragma unroll
            for (int n2 = 0; n2 < 2; n2++) {
                const float q = acc[mf * 2 + n2][reg];
                const float p = plrow[n2 * 32];
                tot += (q + p * (rs - 2.0f * q)) * rcp_cp[n2];
            }
        }
    }
    for (int o = 32; o; o >>= 1) tot += __shfl_down(tot, o, 64);
    if (lane == 0) red[wv] = tot;
    __syncthreads();
    if (tid == 0) atomicAdd(out, red[0] + red[1] + red[2] + red[3]);
}

extern "C" void kernel_launch(void* const* d_in, const int* in_sizes, int n_in,
                              void* d_out, int out_size, void* d_ws, size_t ws_size,
                              hipStream_t stream) {
    const float* w  = (const float*)d_in[0];
    const float* pl = (const float*)d_in[1];
    const float* pr = (const float*)d_in[2];
    const float* cp = (const float*)d_in[3];
    float* out = (float*)d_out;

    u16* Bpack = (u16*)d_ws;   // 4 MB

    k_prep<<<dim3(512), dim3(256), 0, stream>>>(pr, Bpack, out);
    k_main<<<dim3(128 * NSLAB), dim3(256), 0, stream>>>(w, pl, Bpack, cp, out);
}

// Round 6
// 72.277 us; speedup vs baseline: 1.0353x; 1.0353x over previous
//
#include <hip/hip_runtime.h>
#include <stdint.h>

#define A_DIM 8192
#define B_DIM 8192
#define K_CL  256
#define BM    64
#define BK    64
#define NSLAB 4
#define SLABW (B_DIM / NSLAB)   // 2048
#define NKS   (SLABW / BK)      // 32

typedef short bf16x8 __attribute__((ext_vector_type(8)));
typedef float f32x4  __attribute__((ext_vector_type(4)));
typedef float f32x16 __attribute__((ext_vector_type(16)));
typedef unsigned int uint4v __attribute__((ext_vector_type(4)));
typedef unsigned short u16;

__device__ __forceinline__ u16 f2bf(float f) {
    unsigned int u = __float_as_uint(f);
    u += 0x7fffu + ((u >> 16) & 1u);   // RNE, finite inputs (prep only)
    return (u16)(u >> 16);
}

// ---------- prep: pack p_r into 32x32x16 MFMA B-fragment layout, bf16 ----------
// B-frag element map (32x32x16): col = lane&31, k = (lane>>5)*8 + j
// Bpack[((kb2*8 + c2)*64 + lane)*8 + j] = bf16(p_r[kb2*16 + (lane>>5)*8 + j][c2*32 + (lane&31)])
__global__ __launch_bounds__(256) void k_prep(const float* __restrict__ pr,
                                              u16* __restrict__ Bpack,
                                              float* __restrict__ out) {
    const int kb2 = blockIdx.x;          // 0..511
    const int t = threadIdx.x;
    if (kb2 == 0 && t == 0) out[0] = 0.0f;
    const int lane = t & 63, wv = t >> 6;
    const int l31 = lane & 31, half = lane >> 5;
#pragma unroll
    for (int ci = 0; ci < 2; ci++) {
        const int c2 = wv * 2 + ci;
        float v[8];
#pragma unroll
        for (int j = 0; j < 8; j++)
            v[j] = pr[(size_t)(kb2 * 16 + half * 8 + j) * K_CL + c2 * 32 + l31];
        union { bf16x8 b; unsigned int u[4]; } o;
#pragma unroll
        for (int j = 0; j < 4; j++)
            o.u[j] = (unsigned int)f2bf(v[2 * j]) | ((unsigned int)f2bf(v[2 * j + 1]) << 16);
        *(bf16x8*)(Bpack + ((size_t)(kb2 * 8 + c2) * 64 + lane) * 8) = o.b;
    }
}

// ---------- main: reg-staged bf16 LDS, counted-vmcnt pipeline ----------
__global__ __launch_bounds__(256, 2) void k_main(const float* __restrict__ w,
                                                 const float* __restrict__ pl,
                                                 const u16* __restrict__ Bpack,
                                                 const float* __restrict__ cp,
                                                 float* __restrict__ out) {
    __shared__ u16 Abf[2][BM * BK];      // 2 x 8 KB bf16, row = 128 B, XOR-swizzled
    __shared__ float rowsum[BM];
    __shared__ float red[4];

    const int bid = blockIdx.x;
    const int slab = bid & 3;
    const int m0 = (bid >> 2) * BM;
    const int tid = threadIdx.x;
    const int lane = tid & 63, wv = tid >> 6;
    const int l31 = lane & 31, half = lane >> 5;
    const int kb2base = slab * 128;

    // staging assignment: thread owns row srow, 16 f32 cols scg*16..+15 of each tile
    const int srow = wv * 16 + (lane >> 2);
    const int scg  = lane & 3;
    const float* wthr = w + (size_t)(m0 + srow) * B_DIM + (size_t)slab * SLABW + scg * 16;

    // LDS write byte offsets (fixed per thread), XOR (row&7)<<4 per 16B granule
    const int wb0 = srow * 128 + ((scg * 32)      ^ ((srow & 7) << 4));
    const int wb1 = srow * 128 + ((scg * 32 + 16) ^ ((srow & 7) << 4));

    float rcp_cp[2];
#pragma unroll
    for (int n2 = 0; n2 < 2; n2++)
        rcp_cp[n2] = 1.0f / cp[wv * 64 + n2 * 32 + l31];

    f32x16 acc[4];   // [mf*2+n2]
#pragma unroll
    for (int i = 0; i < 4; i++)
#pragma unroll
        for (int r = 0; r < 16; r++) acc[i][r] = 0.f;
    float sums = 0.f;

#define GLOAD(R, ks) do {                                                                \
        const float* gp_ = wthr + (size_t)(ks) * BK;                                     \
        R##0 = *(const f32x4*)(gp_);                                                     \
        R##1 = *(const f32x4*)(gp_ + 4);                                                 \
        R##2 = *(const f32x4*)(gp_ + 8);                                                 \
        R##3 = *(const f32x4*)(gp_ + 12);                                                \
    } while (0)

#define LOADB(arr, ks) do {                                                              \
        _Pragma("unroll")                                                                \
        for (int kf_ = 0; kf_ < 4; kf_++)                                                \
            _Pragma("unroll")                                                            \
            for (int n2_ = 0; n2_ < 2; n2_++)                                            \
                (arr)[kf_ * 2 + n2_] = *(const bf16x8*)(Bpack +                          \
                    (((size_t)(kb2base + (ks) * 4 + kf_) * 8 + wv * 2 + n2_) * 64 + lane) * 8); \
    } while (0)

#define PERM2(hi, lo) __builtin_amdgcn_perm(__float_as_uint(hi), __float_as_uint(lo), 0x07060302u)

#define CONVERT(R, buf) do {                                                             \
        sums += R##0[0]+R##0[1]+R##0[2]+R##0[3] + R##1[0]+R##1[1]+R##1[2]+R##1[3]        \
              + R##2[0]+R##2[1]+R##2[2]+R##2[3] + R##3[0]+R##3[1]+R##3[2]+R##3[3];       \
        uint4v w0_, w1_;                                                                 \
        w0_[0] = PERM2(R##0[1], R##0[0]); w0_[1] = PERM2(R##0[3], R##0[2]);              \
        w0_[2] = PERM2(R##1[1], R##1[0]); w0_[3] = PERM2(R##1[3], R##1[2]);              \
        w1_[0] = PERM2(R##2[1], R##2[0]); w1_[1] = PERM2(R##2[3], R##2[2]);              \
        w1_[2] = PERM2(R##3[1], R##3[0]); w1_[3] = PERM2(R##3[3], R##3[2]);              \
        *(uint4v*)((char*)&Abf[(buf)][0] + wb0) = w0_;                                   \
        *(uint4v*)((char*)&Abf[(buf)][0] + wb1) = w1_;                                   \
    } while (0)

#define COMPUTE(cur, arr) do {                                                           \
        const char* ab_ = (const char*)&Abf[(cur)][0];                                   \
        const int sx_ = (l31 & 7) << 4;                                                  \
        _Pragma("unroll")                                                                \
        for (int kf_ = 0; kf_ < 4; kf_++) {                                              \
            bf16x8 a0_ = *(const bf16x8*)(ab_ + (l31 * 128        + ((kf_ * 32 + half * 16) ^ sx_))); \
            bf16x8 a1_ = *(const bf16x8*)(ab_ + ((32 + l31) * 128 + ((kf_ * 32 + half * 16) ^ sx_))); \
            acc[0] = __builtin_amdgcn_mfma_f32_32x32x16_bf16(a0_, (arr)[kf_ * 2 + 0], acc[0], 0, 0, 0); \
            acc[1] = __builtin_amdgcn_mfma_f32_32x32x16_bf16(a0_, (arr)[kf_ * 2 + 1], acc[1], 0, 0, 0); \
            acc[2] = __builtin_amdgcn_mfma_f32_32x32x16_bf16(a1_, (arr)[kf_ * 2 + 0], acc[2], 0, 0, 0); \
            acc[3] = __builtin_amdgcn_mfma_f32_32x32x16_bf16(a1_, (arr)[kf_ * 2 + 1], acc[3], 0, 0, 0); \
        }                                                                                \
    } while (0)

#define BODYX(ks, WAITN, BC, BN, RC, RN, DOB, DOG, DOCONV, DOBAR) do {                   \
        if (DOB) LOADB(BN, (ks) + 1);                                                    \
        if (DOG) GLOAD(RN, (ks) + 2);                                                    \
        asm volatile("s_waitcnt vmcnt(" #WAITN ")" ::: "memory");                        \
        __builtin_amdgcn_sched_barrier(0);                                               \
        if (DOCONV) CONVERT(RC, ((ks) + 1) & 1);                                         \
        COMPUTE((ks) & 1, BC);                                                           \
        if (DOBAR) {                                                                     \
            asm volatile("s_waitcnt lgkmcnt(0)" ::: "memory");                           \
            __builtin_amdgcn_s_barrier();                                                \
            __builtin_amdgcn_sched_barrier(0);                                           \
        }                                                                                \
    } while (0)

    f32x4 rA0, rA1, rA2, rA3, rB0, rB1, rB2, rB3;
    bf16x8 bA[8], bB[8];

    // prologue: G0 -> rA, B0 -> bA, G1 -> rB; convert tile0
    GLOAD(rA, 0);
    LOADB(bA, 0);
    GLOAD(rB, 1);
    asm volatile("s_waitcnt vmcnt(12)" ::: "memory");   // rA (G0) arrived
    __builtin_amdgcn_sched_barrier(0);
    CONVERT(rA, 0);
    asm volatile("s_waitcnt lgkmcnt(0)" ::: "memory");
    __builtin_amdgcn_s_barrier();
    __builtin_amdgcn_sched_barrier(0);

    for (int ks = 0; ks < NKS - 2; ks += 2) {   // ks = 0..28
        BODYX(ks,     12, bA, bB, rB, rA, 1, 1, 1, 1);
        BODYX(ks + 1, 12, bB, bA, rA, rB, 1, 1, 1, 1);
    }
    BODYX(30, 8, bA, bB, rB, rA, 1, 0, 1, 1);   // loads B31; converts G31
    BODYX(31, 0, bB, bA, rA, rB, 0, 0, 0, 0);

#undef BODYX
#undef COMPUTE
#undef CONVERT
#undef PERM2
#undef LOADB
#undef GLOAD

    // row sums: lanes 4j..4j+3 hold col-group partials of row srow
    {
        float v = sums;
        v += __shfl_xor(v, 1, 64);
        v += __shfl_xor(v, 2, 64);
        if ((lane & 3) == 0) rowsum[srow] = v;
    }
    __syncthreads();

    // epilogue: tot = sum over (row,col) of [q*(1-2p) + rowW_slab*p] / cp
    // C/D 32x32 layout: col = lane&31, row = (reg&3) + 8*(reg>>2) + 4*(lane>>5)
    float tot = 0.f;
#pragma unroll
    for (int mf = 0; mf < 2; mf++) {
#pragma unroll
        for (int reg = 0; reg < 16; reg++) {
            const int lrow = mf * 32 + (reg & 3) + 8 * (reg >> 2) + 4 * half;
            const float rs = rowsum[lrow];
            const float* plrow = pl + (size_t)(m0 + lrow) * K_CL + wv * 64 + l31;
#pragma unroll
            for (int n2 = 0; n2 < 2; n2++) {
                const float q = acc[mf * 2 + n2][reg];
                const float p = plrow[n2 * 32];
                tot += (q + p * (rs - 2.0f * q)) * rcp_cp[n2];
            }
        }
    }
    for (int o = 32; o; o >>= 1) tot += __shfl_down(tot, o, 64);
    if (lane == 0) red[wv] = tot;
    __syncthreads();
    if (tid == 0) atomicAdd(out, red[0] + red[1] + red[2] + red[3]);
}

extern "C" void kernel_launch(void* const* d_in, const int* in_sizes, int n_in,
                              void* d_out, int out_size, void* d_ws, size_t ws_size,
                              hipStream_t stream) {
    const float* w  = (const float*)d_in[0];
    const float* pl = (const float*)d_in[1];
    const float* pr = (const float*)d_in[2];
    const float* cp = (const float*)d_in[3];
    float* out = (float*)d_out;

    u16* Bpack = (u16*)d_ws;   // 4 MB

    k_prep<<<dim3(512), dim3(256), 0, stream>>>(pr, Bpack, out);
    k_main<<<dim3(128 * NSLAB), dim3(256), 0, stream>>>(w, pl, Bpack, cp, out);
}

// Round 7
// 70.321 us; speedup vs baseline: 1.0641x; 1.0278x over previous
//
#include <hip/hip_runtime.h>
#include <stdint.h>

#define A_DIM 8192
#define B_DIM 8192
#define K_CL  256
#define BM    64
#define BK    64
#define NSLAB 4
#define SLABW (B_DIM / NSLAB)   // 2048
#define NKS   (SLABW / BK)      // 32

typedef short bf16x8 __attribute__((ext_vector_type(8)));
typedef float f32x4  __attribute__((ext_vector_type(4)));
typedef float f32x16 __attribute__((ext_vector_type(16)));
typedef unsigned short u16;

__device__ __forceinline__ u16 f2bf(float f) {
    unsigned int u = __float_as_uint(f);
    u += 0x7fffu + ((u >> 16) & 1u);   // RNE, finite inputs (prep only)
    return (u16)(u >> 16);
}

// ---------- prep: pack p_r into 32x32x16 MFMA B-fragment layout, bf16 ----------
// B-frag element map (32x32x16): col = lane&31, k = (lane>>5)*8 + j
// Bpack[((kb2*8 + c2)*64 + lane)*8 + j] = bf16(p_r[kb2*16 + (lane>>5)*8 + j][c2*32 + (lane&31)])
__global__ __launch_bounds__(256) void k_prep(const float* __restrict__ pr,
                                              u16* __restrict__ Bpack,
                                              float* __restrict__ out) {
    const int kb2 = blockIdx.x;          // 0..511
    const int t = threadIdx.x;
    if (kb2 == 0 && t == 0) out[0] = 0.0f;
    const int lane = t & 63, wv = t >> 6;
    const int l31 = lane & 31, half = lane >> 5;
#pragma unroll
    for (int ci = 0; ci < 2; ci++) {
        const int c2 = wv * 2 + ci;
        float v[8];
#pragma unroll
        for (int j = 0; j < 8; j++)
            v[j] = pr[(size_t)(kb2 * 16 + half * 8 + j) * K_CL + c2 * 32 + l31];
        union { bf16x8 b; unsigned int u[4]; } o;
#pragma unroll
        for (int j = 0; j < 4; j++)
            o.u[j] = (unsigned int)f2bf(v[2 * j]) | ((unsigned int)f2bf(v[2 * j + 1]) << 16);
        *(bf16x8*)(Bpack + ((size_t)(kb2 * 8 + c2) * 64 + lane) * 8) = o.b;
    }
}

// ---------- main: reg-staged bf16 LDS, counted-vmcnt pipeline, contiguous-chunk w loads ----------
__global__ __launch_bounds__(256, 2) void k_main(const float* __restrict__ w,
                                                 const float* __restrict__ pl,
                                                 const u16* __restrict__ Bpack,
                                                 const float* __restrict__ cp,
                                                 float* __restrict__ out) {
    __shared__ u16 Abf[2][BM * BK];      // 2 x 8 KB bf16, row = 128 B, XOR-swizzled
    __shared__ float rowsum[BM];
    __shared__ float red[4];

    const int bid = blockIdx.x;
    const int slab = bid & 3;
    const int m0 = (bid >> 2) * BM;
    const int tid = threadIdx.x;
    const int lane = tid & 63, wv = tid >> 6;
    const int l31 = lane & 31, half = lane >> 5;
    const int kb2base = slab * 128;

    // staging: piece i (0..3) of wave wv -> row = wv*16 + i*4 + (lane>>4), 16B at col (lane&15)*4.
    // Each instruction covers a contiguous 1 KB chunk (4 rows x 256 B): 8 L2-line requests (minimal).
    const int g4  = lane >> 4;           // 0..3
    const int c16 = lane & 15;           // col chunk
    const float* wthr = w + (size_t)(m0 + wv * 16 + g4) * B_DIM + (size_t)slab * SLABW + c16 * 4;

    // LDS write byte offsets per piece (8 B each), XOR (row&7)<<4 on 16-B granules
    int wb[4];
#pragma unroll
    for (int i = 0; i < 4; i++) {
        const int row = wv * 16 + i * 4 + g4;
        wb[i] = row * 128 + ((c16 * 8) ^ ((row & 7) << 4));
    }

    float rcp_cp[2];
#pragma unroll
    for (int n2 = 0; n2 < 2; n2++)
        rcp_cp[n2] = 1.0f / cp[wv * 64 + n2 * 32 + l31];

    f32x16 acc[4];   // [mf*2+n2]
#pragma unroll
    for (int i = 0; i < 4; i++)
#pragma unroll
        for (int r = 0; r < 16; r++) acc[i][r] = 0.f;
    float sm0 = 0.f, sm1 = 0.f, sm2 = 0.f, sm3 = 0.f;

#define GLOAD(R, ks) do {                                                                \
        const float* gp_ = wthr + (size_t)(ks) * BK;                                     \
        R##0 = *(const f32x4*)(gp_);                                                     \
        R##1 = *(const f32x4*)(gp_ + 4 * B_DIM);                                         \
        R##2 = *(const f32x4*)(gp_ + 8 * B_DIM);                                         \
        R##3 = *(const f32x4*)(gp_ + 12 * B_DIM);                                        \
    } while (0)

#define LOADB(arr, ks) do {                                                              \
        _Pragma("unroll")                                                                \
        for (int kf_ = 0; kf_ < 4; kf_++)                                                \
            _Pragma("unroll")                                                            \
            for (int n2_ = 0; n2_ < 2; n2_++)                                            \
                (arr)[kf_ * 2 + n2_] = *(const bf16x8*)(Bpack +                          \
                    (((size_t)(kb2base + (ks) * 4 + kf_) * 8 + wv * 2 + n2_) * 64 + lane) * 8); \
    } while (0)

#define PERM2(hi, lo) __builtin_amdgcn_perm(__float_as_uint(hi), __float_as_uint(lo), 0x07060302u)

#define CONVERT(R, buf) do {                                                             \
        sm0 += R##0[0] + R##0[1] + R##0[2] + R##0[3];                                    \
        sm1 += R##1[0] + R##1[1] + R##1[2] + R##1[3];                                    \
        sm2 += R##2[0] + R##2[1] + R##2[2] + R##2[3];                                    \
        sm3 += R##3[0] + R##3[1] + R##3[2] + R##3[3];                                    \
        uint2 p0_, p1_, p2_, p3_;                                                        \
        p0_.x = PERM2(R##0[1], R##0[0]); p0_.y = PERM2(R##0[3], R##0[2]);                \
        p1_.x = PERM2(R##1[1], R##1[0]); p1_.y = PERM2(R##1[3], R##1[2]);                \
        p2_.x = PERM2(R##2[1], R##2[0]); p2_.y = PERM2(R##2[3], R##2[2]);                \
        p3_.x = PERM2(R##3[1], R##3[0]); p3_.y = PERM2(R##3[3], R##3[2]);                \
        char* lb_ = (char*)&Abf[(buf)][0];                                               \
        *(uint2*)(lb_ + wb[0]) = p0_;                                                    \
        *(uint2*)(lb_ + wb[1]) = p1_;                                                    \
        *(uint2*)(lb_ + wb[2]) = p2_;                                                    \
        *(uint2*)(lb_ + wb[3]) = p3_;                                                    \
    } while (0)

#define COMPUTE(cur, arr) do {                                                           \
        const char* ab_ = (const char*)&Abf[(cur)][0];                                   \
        const int sx_ = (l31 & 7) << 4;                                                  \
        _Pragma("unroll")                                                                \
        for (int kf_ = 0; kf_ < 4; kf_++) {                                              \
            bf16x8 a0_ = *(const bf16x8*)(ab_ + (l31 * 128        + ((kf_ * 32 + half * 16) ^ sx_))); \
            bf16x8 a1_ = *(const bf16x8*)(ab_ + ((32 + l31) * 128 + ((kf_ * 32 + half * 16) ^ sx_))); \
            acc[0] = __builtin_amdgcn_mfma_f32_32x32x16_bf16(a0_, (arr)[kf_ * 2 + 0], acc[0], 0, 0, 0); \
            acc[1] = __builtin_amdgcn_mfma_f32_32x32x16_bf16(a0_, (arr)[kf_ * 2 + 1], acc[1], 0, 0, 0); \
            acc[2] = __builtin_amdgcn_mfma_f32_32x32x16_bf16(a1_, (arr)[kf_ * 2 + 0], acc[2], 0, 0, 0); \
            acc[3] = __builtin_amdgcn_mfma_f32_32x32x16_bf16(a1_, (arr)[kf_ * 2 + 1], acc[3], 0, 0, 0); \
        }                                                                                \
    } while (0)

#define BODYX(ks, WAITN, BC, BN, RC, RN, DOB, DOG, DOCONV, DOBAR) do {                   \
        if (DOB) LOADB(BN, (ks) + 1);                                                    \
        if (DOG) GLOAD(RN, (ks) + 2);                                                    \
        asm volatile("s_waitcnt vmcnt(" #WAITN ")" ::: "memory");                        \
        __builtin_amdgcn_sched_barrier(0);                                               \
        if (DOCONV) CONVERT(RC, ((ks) + 1) & 1);                                         \
        COMPUTE((ks) & 1, BC);                                                           \
        if (DOBAR) {                                                                     \
            asm volatile("s_waitcnt lgkmcnt(0)" ::: "memory");                           \
            __builtin_amdgcn_s_barrier();                                                \
            __builtin_amdgcn_sched_barrier(0);                                           \
        }                                                                                \
    } while (0)

    f32x4 rA0, rA1, rA2, rA3, rB0, rB1, rB2, rB3;
    bf16x8 bA[8], bB[8];

    // prologue: G0 -> rA, B0 -> bA, G1 -> rB; convert tile0
    GLOAD(rA, 0);
    LOADB(bA, 0);
    GLOAD(rB, 1);
    asm volatile("s_waitcnt vmcnt(12)" ::: "memory");   // rA (G0) arrived
    __builtin_amdgcn_sched_barrier(0);
    CONVERT(rA, 0);
    asm volatile("s_waitcnt lgkmcnt(0)" ::: "memory");
    __builtin_amdgcn_s_barrier();
    __builtin_amdgcn_sched_barrier(0);

    for (int ks = 0; ks < NKS - 2; ks += 2) {   // ks = 0..28
        BODYX(ks,     12, bA, bB, rB, rA, 1, 1, 1, 1);
        BODYX(ks + 1, 12, bB, bA, rA, rB, 1, 1, 1, 1);
    }
    BODYX(30, 8, bA, bB, rB, rA, 1, 0, 1, 1);   // loads B31; converts G31
    BODYX(31, 0, bB, bA, rA, rB, 0, 0, 0, 0);

#undef BODYX
#undef COMPUTE
#undef CONVERT
#undef PERM2
#undef LOADB
#undef GLOAD

    // row sums: piece i of this thread holds cols c16*16.. of row wv*16+i*4+g4;
    // reduce across the 16-lane col group (xor 1,2,4,8 preserves g4)
    {
        float v0 = sm0, v1 = sm1, v2 = sm2, v3 = sm3;
#pragma unroll
        for (int o = 1; o <= 8; o <<= 1) {
            v0 += __shfl_xor(v0, o, 64);
            v1 += __shfl_xor(v1, o, 64);
            v2 += __shfl_xor(v2, o, 64);
            v3 += __shfl_xor(v3, o, 64);
        }
        if (c16 == 0) {
            rowsum[wv * 16 + 0 + g4]  = v0;
            rowsum[wv * 16 + 4 + g4]  = v1;
            rowsum[wv * 16 + 8 + g4]  = v2;
            rowsum[wv * 16 + 12 + g4] = v3;
        }
    }
    __syncthreads();

    // epilogue: tot = sum over (row,col) of [q*(1-2p) + rowW_slab*p] / cp
    // C/D 32x32 layout: col = lane&31, row = (reg&3) + 8*(reg>>2) + 4*(lane>>5)
    float tot = 0.f;
#pragma unroll
    for (int mf = 0; mf < 2; mf++) {
#pragma unroll
        for (int reg = 0; reg < 16; reg++) {
            const int lrow = mf * 32 + (reg & 3) + 8 * (reg >> 2) + 4 * half;
            const float rs = rowsum[lrow];
            const float* plrow = pl + (size_t)(m0 + lrow) * K_CL + wv * 64 + l31;
#pragma unroll
            for (int n2 = 0; n2 < 2; n2++) {
                const float q = acc[mf * 2 + n2][reg];
                const float p = plrow[n2 * 32];
                tot += (q + p * (rs - 2.0f * q)) * rcp_cp[n2];
            }
        }
    }
    for (int o = 32; o; o >>= 1) tot += __shfl_down(tot, o, 64);
    if (lane == 0) red[wv] = tot;
    __syncthreads();
    if (tid == 0) atomicAdd(out, red[0] + red[1] + red[2] + red[3]);
}

extern "C" void kernel_launch(void* const* d_in, const int* in_sizes, int n_in,
                              void* d_out, int out_size, void* d_ws, size_t ws_size,
                              hipStream_t stream) {
    const float* w  = (const float*)d_in[0];
    const float* pl = (const float*)d_in[1];
    const float* pr = (const float*)d_in[2];
    const float* cp = (const float*)d_in[3];
    float* out = (float*)d_out;

    u16* Bpack = (u16*)d_ws;   // 4 MB

    k_prep<<<dim3(512), dim3(256), 0, stream>>>(pr, Bpack, out);
    k_main<<<dim3(128 * NSLAB), dim3(256), 0, stream>>>(w, pl, Bpack, cp, out);
}